// Round 13
// baseline (61.589 us; speedup 1.0000x reference)
//
#include <hip/hip_runtime.h>

// LengthRegulator: B=32, L=1024, D=512, T=max_len=4096
// out[b,t,:] = x[b, searchsorted(cumsum(dur[b]), t, 'right'), :], zero for t >= total.
//
// SINGLE fused kernel, 512 blocks x 1024 threads (one round, 2 blocks/CU,
// 2048 threads/CU). Block owns 256 consecutive frames of row b (512 KB writes,
// identical for every block).
// Prologue: scalar dur read (1/thread, coalesced; row re-read by 16 blocks),
//           shfl scan (16 wave partials) -> cum in LDS, 256 threads binary-
//           search the block's 256 frame->token ids.
// Main loop: 8 chunks x 32 frames, one 128-thread quad each; sequential-frame
//           walk with wave-uniform read dedup (token read ~once), contiguous
//           NT stores, pad frames (-1) write zeros.

#define B_ 32
#define L_ 1024
#define D_ 512
#define T_ 4096

typedef float fx4 __attribute__((ext_vector_type(4)));

__global__ __launch_bounds__(1024) void lr_fused(const float* __restrict__ x,
                                                 const int* __restrict__ dur,
                                                 float* __restrict__ out) {
    __shared__ int cum[L_];              // row cumulative sums (4 KB)
    __shared__ int wsum[16];             // 16 waves of 64
    __shared__ int ids[256];             // this block's 256 frame ids
    const int tid = threadIdx.x;
    const int b = blockIdx.x >> 4;       // 16 blocks per row
    const int f0 = (blockIdx.x & 15) * 256;

    // ---- prologue: scan this row's durations into cum (LDS) ----
    int d = dur[b * L_ + tid];
    if (d < 0) d = 0;

    int v = d;
    const int lane = tid & 63;
    #pragma unroll
    for (int off = 1; off < 64; off <<= 1) {
        int n = __shfl_up(v, off, 64);
        if (lane >= off) v += n;
    }
    const int wv = tid >> 6;             // wave index 0..15
    if (lane == 63) wsum[wv] = v;
    __syncthreads();
    int woff = 0;
    #pragma unroll
    for (int w = 0; w < 15; ++w)
        if (w < wv) woff += wsum[w];
    cum[tid] = v + woff;
    __syncthreads();

    // ---- resolve this block's 256 frame ids (10-step LDS binary search) ----
    if (tid < 256) {
        const int t = f0 + tid;
        int idx = -1;                    // -1 => zero-pad frame
        if (t < cum[L_ - 1]) {
            idx = 0;                     // searchsorted(cum, t, 'right')
            #pragma unroll
            for (int s = 512; s > 0; s >>= 1)
                if (cum[idx + s - 1] <= t) idx += s;
        }
        ids[tid] = idx;
    }
    __syncthreads();

    // ---- main loop: quad q handles chunk q (32 sequential frames) ----
    const int quad = tid >> 7;           // 0..7
    const int slot = tid & 127;          // float4 slot within frame

    const fx4* xb = reinterpret_cast<const fx4*>(x) + (size_t)b * (L_ * D_ / 4);
    // global frame base: b*T_ + f0 == blockIdx.x * 256
    fx4* ob = reinterpret_cast<fx4*>(out) +
              ((size_t)blockIdx.x * 256 + quad * 32) * 128;

    int prev = -2;                       // != any id and != -1
    fx4 vv = {0.f, 0.f, 0.f, 0.f};
    #pragma unroll
    for (int fi = 0; fi < 32; ++fi) {
        const int id = ids[quad * 32 + fi];           // broadcast from LDS
        if (id != prev) {                             // wave-uniform branch
            if (id >= 0) vv = xb[id * 128 + slot];    // token read (deduped)
            else         vv = (fx4){0.f, 0.f, 0.f, 0.f};
            prev = id;
        }
        __builtin_nontemporal_store(vv, &ob[fi * 128 + slot]);
    }
}

extern "C" void kernel_launch(void* const* d_in, const int* in_sizes, int n_in,
                              void* d_out, int out_size, void* d_ws, size_t ws_size,
                              hipStream_t stream) {
    const float* x = (const float*)d_in[0];
    const int* dur = (const int*)d_in[1];
    // d_in[2] is max_len (== 4096), compile-time constant here.
    float* out = (float*)d_out;

    lr_fused<<<512, 1024, 0, stream>>>(x, dur, out);
}

// Round 14
// 58.862 us; speedup vs baseline: 1.0463x; 1.0463x over previous
//
#include <hip/hip_runtime.h>

// LengthRegulator: B=32, L=1024, D=512, T=max_len=4096
// out[b,t,:] = x[b, searchsorted(cumsum(dur[b]), t, 'right'), :], zero for t >= total.
//
// FINAL (round-12 optimum): single fused kernel, 1024 blocks x 512 threads
// (one scheduling round, 4 blocks/CU, 2048 threads/CU). Block owns 128
// consecutive frames of row b (= 256 KB of writes, identical for every block).
// Prologue: int2 dur read (4 KB/row, L2-broadcast across 32 blocks/row),
//           512-thread x2 shfl scan -> cum in LDS, 128 threads binary-search
//           the block's 128 frame->token ids.
// Main loop: 4 chunks x 32 frames, one 128-thread quad each; sequential-frame
//           walk with wave-uniform read dedup (token read ~once), contiguous
//           1 KB/wave NT stores, pad frames (-1) write zeros.
//
// Config sweep (measured): 2048x256 = 60.7 us, 1024x512 = 58.7 us,
// 512x1024 = 61.6 us -> 1024x512 is the minimum.

#define B_ 32
#define L_ 1024
#define D_ 512
#define T_ 4096

typedef float fx4 __attribute__((ext_vector_type(4)));

__global__ __launch_bounds__(512) void lr_fused(const float* __restrict__ x,
                                                const int* __restrict__ dur,
                                                float* __restrict__ out) {
    __shared__ int cum[L_];              // row cumulative sums (4 KB)
    __shared__ int wsum[8];              // 8 waves of 64
    __shared__ int ids[128];             // this block's 128 frame ids
    const int tid = threadIdx.x;
    const int b = blockIdx.x >> 5;       // 32 blocks per row
    const int f0 = (blockIdx.x & 31) * 128;

    // ---- prologue: scan this row's durations into cum (LDS) ----
    int2 dv = reinterpret_cast<const int2*>(dur + b * L_)[tid];
    const int a0 = max(dv.x, 0), a1 = max(dv.y, 0);
    const int tsum = a0 + a1;

    int v = tsum;
    const int lane = tid & 63;
    #pragma unroll
    for (int off = 1; off < 64; off <<= 1) {
        int n = __shfl_up(v, off, 64);
        if (lane >= off) v += n;
    }
    const int wv = tid >> 6;             // wave index 0..7
    if (lane == 63) wsum[wv] = v;
    __syncthreads();
    int woff = 0;
    #pragma unroll
    for (int w = 0; w < 7; ++w)
        if (w < wv) woff += wsum[w];
    const int incl = v + woff;
    cum[2 * tid + 0] = incl - a1;
    cum[2 * tid + 1] = incl;
    __syncthreads();

    // ---- resolve this block's 128 frame ids (10-step LDS binary search) ----
    if (tid < 128) {
        const int t = f0 + tid;
        int idx = -1;                    // -1 => zero-pad frame
        if (t < cum[L_ - 1]) {
            idx = 0;                     // searchsorted(cum, t, 'right')
            #pragma unroll
            for (int s = 512; s > 0; s >>= 1)
                if (cum[idx + s - 1] <= t) idx += s;
        }
        ids[tid] = idx;
    }
    __syncthreads();

    // ---- main loop: quad q handles chunk q (32 sequential frames) ----
    const int quad = tid >> 7;           // 0..3
    const int slot = tid & 127;          // float4 slot within frame

    const fx4* xb = reinterpret_cast<const fx4*>(x) + (size_t)b * (L_ * D_ / 4);
    // global frame base: b*T_ + f0 == blockIdx.x * 128
    fx4* ob = reinterpret_cast<fx4*>(out) +
              ((size_t)blockIdx.x * 128 + quad * 32) * 128;

    int prev = -2;                       // != any id and != -1
    fx4 vv = {0.f, 0.f, 0.f, 0.f};
    #pragma unroll
    for (int fi = 0; fi < 32; ++fi) {
        const int id = ids[quad * 32 + fi];           // broadcast from LDS
        if (id != prev) {                             // wave-uniform branch
            if (id >= 0) vv = xb[id * 128 + slot];    // token read (deduped)
            else         vv = (fx4){0.f, 0.f, 0.f, 0.f};
            prev = id;
        }
        __builtin_nontemporal_store(vv, &ob[fi * 128 + slot]);
    }
}

extern "C" void kernel_launch(void* const* d_in, const int* in_sizes, int n_in,
                              void* d_out, int out_size, void* d_ws, size_t ws_size,
                              hipStream_t stream) {
    const float* x = (const float*)d_in[0];
    const int* dur = (const int*)d_in[1];
    // d_in[2] is max_len (== 4096), compile-time constant here.
    float* out = (float*)d_out;

    lr_fused<<<1024, 512, 0, stream>>>(x, dur, out);
}